// Round 1
// baseline (160.429 us; speedup 1.0000x reference)
//
#include <hip/hip_runtime.h>

// out[i,j] = sum_d x[i,d] * Weff[j,d] + b[j]
// Weff[j,d] = W[j,d] + sum_k M[k,d] * W[j, 42+k],  M = connect-4 window masks
// (incl. the reference's bugs: diag windows are full 4x4 blocks; features
// 57..68 have zero masks).

#define NFP 44  // 42 padded to 44 so float4 weight reads tile evenly

__global__ __launch_bounds__(320)
void ddqn_weff(const float* __restrict__ W, float* __restrict__ weff) {
    int tid = threadIdx.x;
    if (tid >= 7 * NFP) return;
    int j  = tid / NFP;
    int dp = tid % NFP;
    float acc = 0.0f;
    if (dp < 42) {
        acc = W[j * 111 + dp];
        int r = dp / 7, c = dp % 7;
        const float* ws = W + j * 111 + 42;
        // 24 row-window features: k = r*4 + i covers cols i..i+3 of row r
        for (int i = 0; i < 4; ++i)
            if (c >= i && c <= i + 3) acc += ws[r * 4 + i];
        // 21 col-window features: k = 24 + c*3 + i covers rows i..i+3 of col c
        for (int i = 0; i < 3; ++i)
            if (r >= i && r <= i + 3) acc += ws[24 + c * 3 + i];
        // 12 "diag" features (reference bug: full 4x4 block):
        // k = 45 + off*4 + col covers rows (2-off)..(5-off), cols col..col+3
        for (int off = 0; off < 3; ++off)
            for (int col = 0; col < 4; ++col)
                if (r >= 2 - off && r <= 5 - off && c >= col && c <= col + 3)
                    acc += ws[45 + off * 4 + col];
        // features 57..68: mask never written in reference -> zero contribution
    }
    weff[tid] = acc;
}

__global__ __launch_bounds__(256)
void ddqn_main(const float* __restrict__ gs,
               const float* __restrict__ weff,
               const float* __restrict__ b,
               float* __restrict__ out) {
    __shared__ float wl[7 * NFP];
    __shared__ float bl[7];
    int t = threadIdx.x;
    for (int i = t; i < 7 * NFP; i += 256) wl[i] = weff[i];
    if (t < 7) bl[t] = b[t];
    __syncthreads();

    size_t gid = (size_t)blockIdx.x * 256 + (size_t)t;  // one thread = 2 rows

    // Load 2 rows = 84 floats = 21 aligned float4 loads (336 B, 16B aligned).
    const float4* src = (const float4*)(gs + gid * 84);
    float xa[NFP], xb[NFP];
    #pragma unroll
    for (int i = 0; i < 21; ++i) {
        float4 v = src[i];
        float vv[4] = {v.x, v.y, v.z, v.w};
        #pragma unroll
        for (int q = 0; q < 4; ++q) {
            int f = i * 4 + q;
            if (f < 42) xa[f] = vv[q];
            else        xb[f - 42] = vv[q];
        }
    }
    xa[42] = xa[43] = 0.0f;
    xb[42] = xb[43] = 0.0f;

    float acc0[7], acc1[7];
    #pragma unroll
    for (int j = 0; j < 7; ++j) { acc0[j] = bl[j]; acc1[j] = bl[j]; }

    // Weights broadcast from LDS as float4 (same address across lanes ->
    // conflict-free broadcast). 11 * 7 = 77 ds_read_b128 per thread.
    #pragma unroll
    for (int d = 0; d < NFP; d += 4) {
        #pragma unroll
        for (int j = 0; j < 7; ++j) {
            const float4 w = *(const float4*)&wl[j * NFP + d];
            acc0[j] += xa[d] * w.x + xa[d + 1] * w.y + xa[d + 2] * w.z + xa[d + 3] * w.w;
            acc1[j] += xb[d] * w.x + xb[d + 1] * w.y + xb[d + 2] * w.z + xb[d + 3] * w.w;
        }
    }

    // 14 contiguous floats out, 8B aligned -> 7 float2 stores.
    float2* o = (float2*)(out + gid * 14);
    o[0] = make_float2(acc0[0], acc0[1]);
    o[1] = make_float2(acc0[2], acc0[3]);
    o[2] = make_float2(acc0[4], acc0[5]);
    o[3] = make_float2(acc0[6], acc1[0]);
    o[4] = make_float2(acc1[1], acc1[2]);
    o[5] = make_float2(acc1[3], acc1[4]);
    o[6] = make_float2(acc1[5], acc1[6]);
}

extern "C" void kernel_launch(void* const* d_in, const int* in_sizes, int n_in,
                              void* d_out, int out_size, void* d_ws, size_t ws_size,
                              hipStream_t stream) {
    const float* gs = (const float*)d_in[0];   // [B, 42] f32
    const float* W  = (const float*)d_in[1];   // [7, 111] f32
    const float* b  = (const float*)d_in[2];   // [7] f32
    float* out  = (float*)d_out;               // [B, 7] f32
    float* weff = (float*)d_ws;                // [7, 44] f32 scratch (1232 B)

    ddqn_weff<<<dim3(1), dim3(320), 0, stream>>>(W, weff);

    int B = in_sizes[0] / 42;                  // 524288
    int nthreads = B / 2;                      // 2 rows per thread
    ddqn_main<<<dim3(nthreads / 256), dim3(256), 0, stream>>>(gs, weff, b, out);
}

// Round 2
// 140.997 us; speedup vs baseline: 1.1378x; 1.1378x over previous
//
#include <hip/hip_runtime.h>

// out[i,j] = sum_d x[i,d] * Weff[j,d] + b[j]
// Weff[j,d] = W[j,d] + sum_k M[k,d] * W[j, 42+k],  M = connect-4 window masks
// (incl. the reference's bugs: diag windows are full 4x4 blocks; features
// 57..68 have zero masks).

#define TILE_ROWS 128
#define ROW_PAD   43   // 42+1: gcd(43,32)=1 -> conflict-free per-row LDS reads

__global__ __launch_bounds__(320)
void ddqn_weff(const float* __restrict__ W, float* __restrict__ weff) {
    int tid = threadIdx.x;
    if (tid >= 7 * 42) return;
    int j = tid / 42;
    int d = tid % 42;
    float acc = W[j * 111 + d];
    int r = d / 7, c = d % 7;
    const float* ws = W + j * 111 + 42;
    // 24 row-window features: k = r*4 + i covers cols i..i+3 of row r
    for (int i = 0; i < 4; ++i)
        if (c >= i && c <= i + 3) acc += ws[r * 4 + i];
    // 21 col-window features: k = 24 + c*3 + i covers rows i..i+3 of col c
    for (int i = 0; i < 3; ++i)
        if (r >= i && r <= i + 3) acc += ws[24 + c * 3 + i];
    // 12 "diag" features (reference bug: full 4x4 block):
    // k = 45 + off*4 + col covers rows (2-off)..(5-off), cols col..col+3
    for (int off = 0; off < 3; ++off)
        for (int col = 0; col < 4; ++col)
            if (r >= 2 - off && r <= 5 - off && c >= col && c <= col + 3)
                acc += ws[45 + off * 4 + col];
    // features 57..68: mask never written in reference -> zero contribution
    weff[j * 42 + d] = acc;
}

__global__ __launch_bounds__(TILE_ROWS)
void ddqn_main(const float* __restrict__ gs,
               const float* __restrict__ weff,
               const float* __restrict__ b,
               float* __restrict__ out) {
    __shared__ float tile[TILE_ROWS * ROW_PAD];
    const int t = threadIdx.x;

    // ---- Stage 128 rows (5376 floats) with fully-coalesced scalar loads.
    // f = k*128 + t: consecutive lanes -> consecutive global addrs (perfect
    // coalescing) AND consecutive padded-LDS addrs (conflict-free writes).
    const float* src = gs + (size_t)blockIdx.x * (TILE_ROWS * 42);
    int row = t / 42;
    int col = t - row * 42;
    #pragma unroll
    for (int k = 0; k < 42; ++k) {
        tile[row * ROW_PAD + col] = src[k * TILE_ROWS + t];
        // advance f by 128 = 3*42 + 2
        row += 3; col += 2;
        if (col >= 42) { col -= 42; row += 1; }
    }
    __syncthreads();

    // ---- Each thread computes one row. x from LDS (stride 43 across lanes,
    // conflict-free); weights via wave-uniform global reads -> s_load / SGPR
    // operands in v_fmac.
    float x[42];
    #pragma unroll
    for (int d = 0; d < 42; ++d) x[d] = tile[t * ROW_PAD + d];

    float acc[7];
    #pragma unroll
    for (int j = 0; j < 7; ++j) acc[j] = b[j];

    #pragma unroll
    for (int d = 0; d < 42; ++d) {
        #pragma unroll
        for (int j = 0; j < 7; ++j)
            acc[j] = fmaf(x[d], weff[j * 42 + d], acc[j]);
    }

    size_t gid = (size_t)blockIdx.x * TILE_ROWS + t;
    float* o = out + gid * 7;
    #pragma unroll
    for (int j = 0; j < 7; ++j) o[j] = acc[j];
}

extern "C" void kernel_launch(void* const* d_in, const int* in_sizes, int n_in,
                              void* d_out, int out_size, void* d_ws, size_t ws_size,
                              hipStream_t stream) {
    const float* gs = (const float*)d_in[0];   // [B, 42] f32
    const float* W  = (const float*)d_in[1];   // [7, 111] f32
    const float* b  = (const float*)d_in[2];   // [7] f32
    float* out  = (float*)d_out;               // [B, 7] f32
    float* weff = (float*)d_ws;                // [7, 42] f32 scratch

    ddqn_weff<<<dim3(1), dim3(320), 0, stream>>>(W, weff);

    int B = in_sizes[0] / 42;                  // 524288
    ddqn_main<<<dim3(B / TILE_ROWS), dim3(TILE_ROWS), 0, stream>>>(gs, weff, b, out);
}